// Round 7
// baseline (180.936 us; speedup 1.0000x reference)
//
#include <hip/hip_runtime.h>
#include <hip/hip_fp16.h>

#define NN 50000
#define NE 800000
#define NG 64
#define DF 96
#define SLOPE 0.2f
#define NBK 196   // (NN+255)/256 buckets of 256 dst nodes
#define EPB 2048  // edges per bin block
#define EB2 391   // ceil(NE/EPB)
#define PC 12     // pool chunks per graph

// ---------------- pass A1: per-block bucket histogram (column-major out) ----------------
__global__ __launch_bounds__(256) void k_hist(const int* __restrict__ dst,
                                              int* __restrict__ hist2d) {
  __shared__ int h[NBK];
  int t = threadIdx.x;
  if (t < NBK) h[t] = 0;
  __syncthreads();
  int base = blockIdx.x * EPB;
  for (int k = 0; k < EPB / 256; ++k) {
    int e = base + k * 256 + t;
    if (e < NE) atomicAdd(&h[dst[e] >> 8], 1);
  }
  __syncthreads();
  if (t < NBK) hist2d[t * EB2 + blockIdx.x] = h[t];
}

// ---------------- scan: bucket bases + per-(block,bucket) offsets (contiguous) ----------------
__global__ __launch_bounds__(256) void k_scanB(const int* __restrict__ hist2d,
                                               int* __restrict__ blockoff,
                                               int* __restrict__ bbase,
                                               const int* __restrict__ batch,
                                               int* __restrict__ gstart,
                                               int* __restrict__ row_start) {
  __shared__ int colsum[256];
  int t = threadIdx.x;
  int s = 0;
  if (t < NBK) {
    const int* col = hist2d + (size_t)t * EB2;
    for (int b = 0; b < EB2; ++b) s += col[b];
  }
  colsum[t] = (t < NBK) ? s : 0;
  __syncthreads();
  for (int o = 1; o < 256; o <<= 1) {
    int v = (t >= o) ? colsum[t - o] : 0;
    __syncthreads();
    colsum[t] += v;
    __syncthreads();
  }
  if (t < NBK) {
    int base = (t == 0) ? 0 : colsum[t - 1];
    bbase[t] = base;
    const int* col = hist2d + (size_t)t * EB2;
    int* boff = blockoff + (size_t)t * EB2;
    int run = base;
    for (int b = 0; b < EB2; ++b) {
      boff[b] = run;
      run += col[b];
    }
  }
  if (t == NBK) bbase[NBK] = NE;
  if (t <= NG) {  // graph bounds (batch sorted)
    int g = t, lo = 0, hi = NN;
    while (lo < hi) {
      int mid = (lo + hi) >> 1;
      if (batch[mid] < g) lo = mid + 1; else hi = mid;
    }
    gstart[g] = lo;
  }
  if (t == 255) row_start[NN] = NE;
}

// ---------------- pass A2: bin edges (deterministic offsets, LDS staged) ----------------
// packed entry: src | ((dst&255)<<16)
__global__ __launch_bounds__(256) void k_bin2(const int* __restrict__ src,
                                              const int* __restrict__ dst,
                                              const int* __restrict__ blockoff,
                                              int* __restrict__ binned) {
  __shared__ int h[NBK], loff[NBK], cur[NBK], gb[NBK];
  __shared__ int tmp[256];
  __shared__ int stage[EPB];
  __shared__ unsigned char sbk[EPB];
  int t = threadIdx.x;
  if (t < NBK) h[t] = 0;
  __syncthreads();
  int base = blockIdx.x * EPB;
  for (int k = 0; k < EPB / 256; ++k) {
    int e = base + k * 256 + t;
    if (e < NE) atomicAdd(&h[dst[e] >> 8], 1);
  }
  __syncthreads();
  tmp[t] = (t < NBK) ? h[t] : 0;
  __syncthreads();
  for (int o = 1; o < 256; o <<= 1) {
    int v = (t >= o) ? tmp[t - o] : 0;
    __syncthreads();
    tmp[t] += v;
    __syncthreads();
  }
  if (t < NBK) {
    int excl = (t == 0) ? 0 : tmp[t - 1];
    loff[t] = excl;
    cur[t] = excl;
    gb[t] = blockoff[(size_t)t * EB2 + blockIdx.x];
  }
  __syncthreads();
  for (int k = 0; k < EPB / 256; ++k) {
    int e = base + k * 256 + t;
    if (e < NE) {
      int d = dst[e];
      int b = d >> 8;
      int p = atomicAdd(&cur[b], 1);
      stage[p] = src[e] | ((d & 255) << 16);
      sbk[p] = (unsigned char)b;
    }
  }
  __syncthreads();
  int tot = min(EPB, NE - base);
  for (int i = t; i < tot; i += 256) {
    int b = sbk[i];
    binned[gb[b] + (i - loff[b])] = stage[i];
  }
}

// ---------------- pass B: per-bucket CSR build + dinv/row_start ----------------
__global__ __launch_bounds__(256) void k_csr(const int* __restrict__ binned,
                                             const int* __restrict__ bbase,
                                             float* __restrict__ dinv,
                                             int* __restrict__ row_start,
                                             unsigned short* __restrict__ csr_src) {
  __shared__ int h[256], cur[256], tmp[256];
  int t = threadIdx.x;
  int b = blockIdx.x;
  int ebeg = bbase[b], eend = bbase[b + 1];
  h[t] = 0;
  __syncthreads();
  for (int i = ebeg + t; i < eend; i += 256) atomicAdd(&h[(unsigned)binned[i] >> 16], 1);
  __syncthreads();
  tmp[t] = h[t];
  __syncthreads();
  for (int o = 1; o < 256; o <<= 1) {
    int v = (t >= o) ? tmp[t - o] : 0;
    __syncthreads();
    tmp[t] += v;
    __syncthreads();
  }
  int excl = (t == 0) ? 0 : tmp[t - 1];
  int rs = ebeg + excl;
  cur[t] = rs;
  int n = b * 256 + t;
  if (n < NN) {
    row_start[n] = rs;
    dinv[n] = rsqrtf((float)h[t] + 1.0f);
  }
  __syncthreads();
  for (int i = ebeg + t; i < eend; i += 256) {
    int pr = binned[i];
    int p = atomicAdd(&cur[(unsigned)pr >> 16], 1);
    csr_src[p] = (unsigned short)(pr & 0xFFFF);
  }
}

// ---------------- G(fp16) = (X @ W) * dinv[row]; X fp32 or fp16 ----------------
// xt is k-major transposed: xt[k][row], stride 68 (16B-aligned float4 reads, r0%4==0)
#define GR 64
#define XTS 68
template <typename T>
__global__ __launch_bounds__(256) void k_gemm(const T* __restrict__ X,
                                              const float* __restrict__ W,
                                              const float* __restrict__ dinv,
                                              __half* __restrict__ G) {
  __shared__ float Ws[DF * DF];   // 36.9 KB
  __shared__ float xt[DF * XTS];  // 26.1 KB
  int t = threadIdx.x;
  int rb = blockIdx.x * GR;
  for (int i = t; i < DF * DF / 4; i += 256)
    ((float4*)Ws)[i] = ((const float4*)W)[i];
  for (int i = t; i < GR * DF / 4; i += 256) {
    int r = i / 24, c4 = i % 24;
    int row = rb + r;
    float4 v = {0.f, 0.f, 0.f, 0.f};
    if (row < NN) {
      if constexpr (sizeof(T) == 4) {
        v = ((const float4*)((const float*)X + (size_t)row * DF))[c4];
      } else {
        uint2 hv = ((const uint2*)((const __half*)X + (size_t)row * DF))[c4];
        float2 a = __half22float2(*(__half2*)&hv.x);
        float2 b = __half22float2(*(__half2*)&hv.y);
        v = float4{a.x, a.y, b.x, b.y};
      }
    }
    xt[(4 * c4 + 0) * XTS + r] = v.x;
    xt[(4 * c4 + 1) * XTS + r] = v.y;
    xt[(4 * c4 + 2) * XTS + r] = v.z;
    xt[(4 * c4 + 3) * XTS + r] = v.w;
  }
  __syncthreads();
  int tc = t & 15;
  int tr = t >> 4;
  int c0 = tc * 6;
  int r0 = tr * 4;
  float acc[4][6];
#pragma unroll
  for (int i = 0; i < 4; ++i)
#pragma unroll
    for (int j = 0; j < 6; ++j) acc[i][j] = 0.f;

#pragma unroll 4
  for (int k = 0; k < DF; ++k) {
    float4 xv = *(const float4*)&xt[k * XTS + r0];
    float2 w0 = *(float2*)&Ws[k * DF + c0];
    float2 w1 = *(float2*)&Ws[k * DF + c0 + 2];
    float2 w2 = *(float2*)&Ws[k * DF + c0 + 4];
    float xr[4] = {xv.x, xv.y, xv.z, xv.w};
    float wv[6] = {w0.x, w0.y, w1.x, w1.y, w2.x, w2.y};
#pragma unroll
    for (int i = 0; i < 4; ++i)
#pragma unroll
      for (int j = 0; j < 6; ++j) acc[i][j] = fmaf(xr[i], wv[j], acc[i][j]);
  }
#pragma unroll
  for (int i = 0; i < 4; ++i) {
    int row = rb + r0 + i;
    if (row < NN) {
      float dv = dinv[row];
      __half2* gp = (__half2*)(G + (size_t)row * DF + c0);
#pragma unroll
      for (int j = 0; j < 3; ++j)
        gp[j] = __floats2half2_rn(acc[i][2 * j] * dv, acc[i][2 * j + 1] * dv);
    }
  }
}

// ---------------- gather-aggregate: 16 lanes/node, fp16 in, fp16 out ----------------
__global__ __launch_bounds__(256) void k_agg(const __half* __restrict__ G,
                                             const float* __restrict__ dinv,
                                             const float* __restrict__ bias,
                                             const int* __restrict__ row_start,
                                             const unsigned short* __restrict__ csr_src,
                                             __half* __restrict__ H) {
  int lane = threadIdx.x & 15;
  int n = blockIdx.x * 16 + (threadIdx.x >> 4);
  if (n >= NN) return;
  const unsigned* rn = (const unsigned*)(G + (size_t)n * DF);
  unsigned su0 = rn[lane], su1 = rn[lane + 16], su2 = rn[lane + 32];
  float2 f0 = __half22float2(*(__half2*)&su0);
  float2 f1 = __half22float2(*(__half2*)&su1);
  float2 f2 = __half22float2(*(__half2*)&su2);
  float a00 = f0.x, a01 = f0.y, a10 = f1.x, a11 = f1.y, a20 = f2.x, a21 = f2.y;

  int s = row_start[n], e = row_start[n + 1];
  for (int j0 = s; j0 < e; j0 += 16) {
    int my = (j0 + lane < e) ? (int)csr_src[j0 + lane] : 0;
    int cnt = min(16, e - j0);
    int jj = 0;
    for (; jj + 8 <= cnt; jj += 8) {
      unsigned u[8][3];
#pragma unroll
      for (int q = 0; q < 8; ++q) {
        int srcn = __shfl(my, jj + q, 16);
        const unsigned* r2 = (const unsigned*)(G + (size_t)srcn * DF);
        u[q][0] = r2[lane];
        u[q][1] = r2[lane + 16];
        u[q][2] = r2[lane + 32];
      }
#pragma unroll
      for (int q = 0; q < 8; ++q) {
        float2 g0 = __half22float2(*(__half2*)&u[q][0]);
        float2 g1 = __half22float2(*(__half2*)&u[q][1]);
        float2 g2 = __half22float2(*(__half2*)&u[q][2]);
        a00 += g0.x; a01 += g0.y;
        a10 += g1.x; a11 += g1.y;
        a20 += g2.x; a21 += g2.y;
      }
    }
    for (; jj < cnt; ++jj) {
      int srcn = __shfl(my, jj, 16);
      const unsigned* r2 = (const unsigned*)(G + (size_t)srcn * DF);
      unsigned v0 = r2[lane], v1 = r2[lane + 16], v2 = r2[lane + 32];
      float2 g0 = __half22float2(*(__half2*)&v0);
      float2 g1 = __half22float2(*(__half2*)&v1);
      float2 g2 = __half22float2(*(__half2*)&v2);
      a00 += g0.x; a01 += g0.y;
      a10 += g1.x; a11 += g1.y;
      a20 += g2.x; a21 += g2.y;
    }
  }
  float dv = dinv[n];
  float2 b0 = *(const float2*)(bias + 2 * lane);
  float2 b1 = *(const float2*)(bias + 2 * lane + 32);
  float2 b2 = *(const float2*)(bias + 2 * lane + 64);
  float v00 = dv * a00 + b0.x, v01 = dv * a01 + b0.y;
  float v10 = dv * a10 + b1.x, v11 = dv * a11 + b1.y;
  float v20 = dv * a20 + b2.x, v21 = dv * a21 + b2.y;
  v00 = v00 > 0.f ? v00 : SLOPE * v00;
  v01 = v01 > 0.f ? v01 : SLOPE * v01;
  v10 = v10 > 0.f ? v10 : SLOPE * v10;
  v11 = v11 > 0.f ? v11 : SLOPE * v11;
  v20 = v20 > 0.f ? v20 : SLOPE * v20;
  v21 = v21 > 0.f ? v21 : SLOPE * v21;
  __half2* hp = (__half2*)(H + (size_t)n * DF);
  hp[lane] = __floats2half2_rn(v00, v01);
  hp[lane + 16] = __floats2half2_rn(v10, v11);
  hp[lane + 32] = __floats2half2_rn(v20, v21);
}

// ---------------- pool stage 1: 12 chunks per graph (fp16 in, fp32 partials) ----------------
__global__ __launch_bounds__(384) void k_pool2(const __half* __restrict__ H,
                                               const int* __restrict__ gstart,
                                               float* __restrict__ partial) {
  int g = blockIdx.x / PC, c = blockIdx.x % PC;
  int f2 = threadIdx.x % 48;
  int r = threadIdx.x / 48;
  int s = gstart[g], e = gstart[g + 1];
  int len = (e - s + PC - 1) / PC;
  int cs = s + c * len, ce = min(cs + len, e);
  float ax = 0.f, ay = 0.f;
  for (int n = cs + r; n < ce; n += 8) {
    float2 v = __half22float2(((const __half2*)(H + (size_t)n * DF))[f2]);
    ax += v.x;
    ay += v.y;
  }
  __shared__ float2 red[8][48];
  red[r][f2] = float2{ax, ay};
  __syncthreads();
  if (r == 0) {
    float sx = 0.f, sy = 0.f;
#pragma unroll
    for (int q = 0; q < 8; ++q) { sx += red[q][f2].x; sy += red[q][f2].y; }
    partial[(size_t)blockIdx.x * DF + 2 * f2] = sx;
    partial[(size_t)blockIdx.x * DF + 2 * f2 + 1] = sy;
  }
}

// ---------------- pool stage 2 + classifier ----------------
__global__ __launch_bounds__(128) void k_pool3(const float* __restrict__ partial,
                                               const int* __restrict__ gstart,
                                               const float* __restrict__ Wc,
                                               const float* __restrict__ bc,
                                               float* __restrict__ out) {
  __shared__ float pm[DF];
  int g = blockIdx.x;
  int t = threadIdx.x;
  if (t < DF) {
    float s = 0.f;
    for (int c = 0; c < PC; ++c) s += partial[(size_t)(g * PC + c) * DF + t];
    float cnt = (float)(gstart[g + 1] - gstart[g]);
    pm[t] = s / fmaxf(cnt, 1.0f);
  }
  __syncthreads();
  if (t < 2) {
    float s = 0.f;
    for (int c = 0; c < DF; ++c) s += pm[c] * Wc[c * 2 + t];
    out[g * 2 + t] = s + bc[t];
  }
}

extern "C" void kernel_launch(void* const* d_in, const int* in_sizes, int n_in,
                              void* d_out, int out_size, void* d_ws, size_t ws_size,
                              hipStream_t stream) {
  const float* x = (const float*)d_in[0];
  const int* ei = (const int*)d_in[1];
  const int* batch = (const int*)d_in[2];
  const float* W1 = (const float*)d_in[3];
  const float* b1 = (const float*)d_in[4];
  const float* W2 = (const float*)d_in[5];
  const float* b2 = (const float*)d_in[6];
  const float* Wc = (const float*)d_in[7];
  const float* bc = (const float*)d_in[8];
  float* out = (float*)d_out;
  const int* srcv = ei;
  const int* dstv = ei + NE;

  char* p = (char*)d_ws;
  auto alloc = [&](size_t bytes) {
    char* r = p;
    p += (bytes + 255) & ~(size_t)255;
    return r;
  };
  int* hist2d = (int*)alloc((size_t)NBK * EB2 * sizeof(int));
  int* blockoff = (int*)alloc((size_t)NBK * EB2 * sizeof(int));
  int* bbase = (int*)alloc((size_t)(NBK + 1) * sizeof(int));
  int* gstart = (int*)alloc((size_t)(NG + 1) * sizeof(int));
  int* row_start = (int*)alloc((size_t)(NN + 1) * sizeof(int));
  int* binned = (int*)alloc((size_t)NE * sizeof(int));
  unsigned short* csr_src = (unsigned short*)alloc((size_t)NE * sizeof(unsigned short));
  float* dinv = (float*)alloc((size_t)NN * sizeof(float));
  __half* g = (__half*)alloc((size_t)NN * DF * sizeof(__half));
  __half* h = (__half*)alloc((size_t)NN * DF * sizeof(__half));
  float* partial = (float*)alloc((size_t)NG * PC * DF * sizeof(float));

  k_hist<<<EB2, 256, 0, stream>>>(dstv, hist2d);
  k_scanB<<<1, 256, 0, stream>>>(hist2d, blockoff, bbase, batch, gstart, row_start);
  k_bin2<<<EB2, 256, 0, stream>>>(srcv, dstv, blockoff, binned);
  k_csr<<<NBK, 256, 0, stream>>>(binned, bbase, dinv, row_start, csr_src);

  k_gemm<float><<<(NN + GR - 1) / GR, 256, 0, stream>>>(x, W1, dinv, g);
  k_agg<<<NN / 16, 256, 0, stream>>>(g, dinv, b1, row_start, csr_src, h);
  k_gemm<__half><<<(NN + GR - 1) / GR, 256, 0, stream>>>(h, W2, dinv, g);
  k_agg<<<NN / 16, 256, 0, stream>>>(g, dinv, b2, row_start, csr_src, h);

  k_pool2<<<NG * PC, 384, 0, stream>>>(h, gstart, partial);
  k_pool3<<<NG, 128, 0, stream>>>(partial, gstart, Wc, bc, out);
}